// Round 3
// baseline (34.572 us; speedup 1.0000x reference)
//
#include <hip/hip_runtime.h>
#include <math.h>

#define NQ 5
#define D 512
#define R 4            // rows per wave, one-shot (no loop)
#define HALF_PI 1.57079632679489662f

typedef float f32x4 __attribute__((ext_vector_type(4)));

// Analytic circuit collapse:
// z_w = -sin(HALF_PI * tanh(pre_w)) * cos(q_params[w])
// zvals = {z1 z2 z3 z4, z0 z1, z0 z1 z2, z0 z1 z2 z3, z0 z1 z2 z3 z4}
// out   = zvals @ w_post.T + b_post

// Butterfly add with DPP (pure VALU, no LDS pipe, ~4 cyc each).
#define DPP_ADD(v, CTRL)                                                        \
    ((v) + __builtin_bit_cast(float, __builtin_amdgcn_update_dpp(               \
               0, __builtin_bit_cast(int, (v)), (CTRL), 0xF, 0xF, true)))

// Full 64-lane sum -> wave-uniform scalar.
__device__ __forceinline__ float wave_sum(float v) {
    v = DPP_ADD(v, 0xB1);   // quad_perm(1,0,3,2): xor 1
    v = DPP_ADD(v, 0x4E);   // quad_perm(2,3,0,1): xor 2
    v = DPP_ADD(v, 0x141);  // row_half_mirror: xor 4 (quads already uniform)
    v = DPP_ADD(v, 0x140);  // row_mirror: xor 8 (8-groups already uniform)
    int vi = __builtin_amdgcn_ds_swizzle(__builtin_bit_cast(int, v), 0x401F); // xor 16 (within 32)
    v = v + __builtin_bit_cast(float, vi);
    // each 32-half now uniform; combine halves via readlane
    const int vb = __builtin_bit_cast(int, v);
    const float lo = __builtin_bit_cast(float, __builtin_amdgcn_readlane(vb, 0));
    const float hi = __builtin_bit_cast(float, __builtin_amdgcn_readlane(vb, 32));
    return lo + hi;
}

__global__ __launch_bounds__(256) void dressed_qnet_kernel(
    const float* __restrict__ x,        // (B, 512)
    const float* __restrict__ w_pre,    // (5, 512)
    const float* __restrict__ b_pre,    // (5,)
    const float* __restrict__ q_params, // (5,)
    const float* __restrict__ w_post,   // (2, 5)
    const float* __restrict__ b_post,   // (2,)
    float* __restrict__ out,            // (B, 2)
    int B)
{
    const int lane = threadIdx.x & 63;
    const int wave = (blockIdx.x * blockDim.x + threadIdx.x) >> 6;
    const int row0 = wave * R;
    if (row0 >= B) return;

    // ---- Issue all R*2 streaming loads FIRST (max loads in flight) ----
    f32x4 xa[R], xb[R];
#pragma unroll
    for (int r = 0; r < R; ++r) {
        const int row = (row0 + r < B) ? (row0 + r) : (B - 1);
        const f32x4* xr = reinterpret_cast<const f32x4*>(x + (size_t)row * D);
        xa[r] = __builtin_nontemporal_load(xr + lane);
        xb[r] = __builtin_nontemporal_load(xr + lane + 64);
    }

    // ---- Per-lane register slice of w_pre (L2-hot, reused by every wave) ----
    f32x4 w0[NQ], w1[NQ];
#pragma unroll
    for (int q = 0; q < NQ; ++q) {
        w0[q] = *reinterpret_cast<const f32x4*>(w_pre + q * D + lane * 4);
        w1[q] = *reinterpret_cast<const f32x4*>(w_pre + q * D + 256 + lane * 4);
    }

    float bp[NQ], ct[NQ], wp0[NQ], wp1[NQ];
#pragma unroll
    for (int q = 0; q < NQ; ++q) {
        bp[q]  = b_pre[q];
        ct[q]  = __cosf(q_params[q]);
        wp0[q] = w_post[q];
        wp1[q] = w_post[NQ + q];
    }
    const float bpost0 = b_post[0];
    const float bpost1 = b_post[1];

    // ---- Partial dots: R*NQ independent FMA chains ----
    float acc[R][NQ];
#pragma unroll
    for (int r = 0; r < R; ++r) {
#pragma unroll
        for (int q = 0; q < NQ; ++q) {
            float s;
            s = xa[r].x * w0[q].x;
            s = fmaf(xa[r].y, w0[q].y, s);
            s = fmaf(xa[r].z, w0[q].z, s);
            s = fmaf(xa[r].w, w0[q].w, s);
            s = fmaf(xb[r].x, w1[q].x, s);
            s = fmaf(xb[r].y, w1[q].y, s);
            s = fmaf(xb[r].z, w1[q].z, s);
            s = fmaf(xb[r].w, w1[q].w, s);
            acc[r][q] = s;
        }
    }

    // ---- 20 independent wave reductions (DPP, short latency, high ILP) ----
#pragma unroll
    for (int r = 0; r < R; ++r)
#pragma unroll
        for (int q = 0; q < NQ; ++q)
            acc[r][q] = wave_sum(acc[r][q]);

    // ---- Epilogue (wave-uniform) ----
    float o[R][2];
#pragma unroll
    for (int r = 0; r < R; ++r) {
        float z[NQ];
#pragma unroll
        for (int q = 0; q < NQ; ++q) {
            const float p = acc[r][q] + bp[q];
            const float e = __expf(2.0f * p);
            const float th = 1.0f - 2.0f / (e + 1.0f);     // tanh(p)
            z[q] = -__sinf(HALF_PI * th) * ct[q];
        }
        const float v1   = z[0] * z[1];
        const float z234 = z[2] * z[3] * z[4];
        const float v0   = z[1] * z234;
        const float v2   = v1 * z[2];
        const float v3   = v2 * z[3];
        const float v4   = v1 * z234;

        float o0 = bpost0, o1 = bpost1;
        o0 = fmaf(wp0[0], v0, o0); o1 = fmaf(wp1[0], v0, o1);
        o0 = fmaf(wp0[1], v1, o0); o1 = fmaf(wp1[1], v1, o1);
        o0 = fmaf(wp0[2], v2, o0); o1 = fmaf(wp1[2], v2, o1);
        o0 = fmaf(wp0[3], v3, o0); o1 = fmaf(wp1[3], v3, o1);
        o0 = fmaf(wp0[4], v4, o0); o1 = fmaf(wp1[4], v4, o1);
        o[r][0] = o0; o[r][1] = o1;
    }

    // ---- Coalesced store: 4 rows x float2 = 32 B from lane 0 ----
    if (lane == 0) {
        if (row0 + R <= B) {
            f32x4* dst = reinterpret_cast<f32x4*>(out + (size_t)row0 * 2);
            f32x4 d0 = { o[0][0], o[0][1], o[1][0], o[1][1] };
            f32x4 d1 = { o[2][0], o[2][1], o[3][0], o[3][1] };
            dst[0] = d0;
            dst[1] = d1;
        } else {
#pragma unroll
            for (int r = 0; r < R; ++r)
                if (row0 + r < B) {
                    out[(size_t)(row0 + r) * 2 + 0] = o[r][0];
                    out[(size_t)(row0 + r) * 2 + 1] = o[r][1];
                }
        }
    }
}

extern "C" void kernel_launch(void* const* d_in, const int* in_sizes, int n_in,
                              void* d_out, int out_size, void* d_ws, size_t ws_size,
                              hipStream_t stream) {
    const float* x        = (const float*)d_in[0];
    const float* w_pre    = (const float*)d_in[1];
    const float* b_pre    = (const float*)d_in[2];
    const float* q_params = (const float*)d_in[3];
    const float* w_post   = (const float*)d_in[4];
    const float* b_post   = (const float*)d_in[5];
    float* out = (float*)d_out;

    const int B = in_sizes[0] / D;   // 65536

    const int threads = 256;                       // 4 waves/block
    const int rows_per_block = (threads / 64) * R; // 16
    const int blocks = (B + rows_per_block - 1) / rows_per_block;  // 4096
    dressed_qnet_kernel<<<blocks, threads, 0, stream>>>(
        x, w_pre, b_pre, q_params, w_post, b_post, out, B);
}